// Round 3
// baseline (1934.543 us; speedup 1.0000x reference)
//
#include <hip/hip_runtime.h>
#include <cstddef>

#define DD 128
#define BN_EPS 1e-5f
#define SLOPE 0.01f
#define BSH 6              // 64 dst rows per bucket
#define BROWS 64

// ---------- bucket histogram: bcnt[b] = #edges with dst>>6 == b ----------
__global__ __launch_bounds__(256) void histb_kernel(const int* __restrict__ dst,
                                                    int* __restrict__ bcnt,
                                                    int E, int NB) {
    __shared__ int bins[1024];
    for (int i = threadIdx.x; i < NB; i += blockDim.x) bins[i] = 0;
    __syncthreads();
    for (int e = blockIdx.x * blockDim.x + threadIdx.x; e < E;
         e += gridDim.x * blockDim.x)
        atomicAdd(&bins[dst[e] >> BSH], 1);
    __syncthreads();
    for (int i = threadIdx.x; i < NB; i += blockDim.x)
        if (bins[i]) atomicAdd(&bcnt[i], bins[i]);
}

// ---------- exclusive scan of bucket counts (NB <= 1024, single block) ----------
__global__ __launch_bounds__(1024) void scanb_kernel(const int* __restrict__ bcnt,
                                                     int* __restrict__ off,
                                                     int* __restrict__ cursor, int NB) {
    __shared__ int s[1024];
    const int t = threadIdx.x;
    int v = (t < NB) ? bcnt[t] : 0;
    s[t] = v;
    __syncthreads();
    for (int d = 1; d < 1024; d <<= 1) {
        int u = (t >= d) ? s[t - d] : 0;
        __syncthreads();
        s[t] += u;
        __syncthreads();
    }
    if (t < NB) {
        int excl = s[t] - v;
        off[t] = excl;
        cursor[t] = excl;
    }
    if (t == 0) off[NB] = s[1023];
}

// ---------- coarse scatter: packed[pos] = (dst&63)<<16 | src ----------
__global__ __launch_bounds__(256) void scatb_kernel(const int* __restrict__ src,
                                                    const int* __restrict__ dst,
                                                    int* __restrict__ cursor,
                                                    unsigned* __restrict__ packed, int E) {
    int e = blockIdx.x * blockDim.x + threadIdx.x;
    if (e >= E) return;
    int d = dst[e];
    int b = d >> BSH;
    int pos = atomicAdd(&cursor[b], 1);
    packed[pos] = ((unsigned)(d & (BROWS - 1)) << 16) | (unsigned)src[e];
}

// ---------- bucketed LDS accumulation: agg rows for one 64-dst bucket ----------
__global__ __launch_bounds__(256) void accumb_kernel(const float* __restrict__ h,
                                                     const int* __restrict__ off,
                                                     const unsigned* __restrict__ packed,
                                                     float* __restrict__ agg, int n) {
    __shared__ float acc[BROWS * DD];   // 32 KB
    const int b = blockIdx.x;
    const int t = threadIdx.x;
    for (int i = t; i < BROWS * DD; i += 256) acc[i] = 0.f;
    __syncthreads();

    const int lane = t & 63;
    const int w = t >> 6;
    const int e0 = off[b];
    const int e1 = off[b + 1];
    for (int base = e0 + w * 64; base < e1; base += 256) {
        int idx = base + lane;
        unsigned pk = (idx < e1) ? packed[idx] : 0u;
        int cnt = min(64, e1 - base);
        for (int j = 0; j < cnt; ++j) {
            unsigned p = __shfl(pk, j);
            int s = (int)(p & 0xffffu);
            int ld = (int)(p >> 16);
            const float* hr = h + (size_t)s * DD;
            float v0 = hr[lane];
            float v1 = hr[64 + lane];
            atomicAdd(&acc[ld * DD + lane], v0);
            atomicAdd(&acc[ld * DD + 64 + lane], v1);
        }
    }
    __syncthreads();

    const int r0 = b << BSH;
    const int rows = min(BROWS, n - r0);
    for (int i = t; i < rows * (DD / 4); i += 256) {
        int r = i >> 5;
        int c = i & 31;
        ((float4*)(agg + (size_t)(r0 + r) * DD))[c] = ((const float4*)(acc + r * DD))[c];
    }
}

// ---------------- GEMM: out[n,128] = act(A[n,128] @ W[128,128] + bias) ----
template <bool FUSE_IN, bool RELU, bool STATS>
__global__ __launch_bounds__(256) void gemm_kernel(
        const float* __restrict__ A0, const float* __restrict__ A1,
        const float* __restrict__ eps_ptr,
        const float* __restrict__ W, const float* __restrict__ bias,
        float* __restrict__ out, float* __restrict__ stats, int n) {
    __shared__ float As[64][36];
    __shared__ float Ws[32][128];
    __shared__ float Ssum[128];
    __shared__ float Ssq[128];

    const int t = threadIdx.x;
    const int cg = t & 31;
    const int rg = t >> 5;
    const int row0 = blockIdx.x * 64;

    float epsval = 1.0f;
    if (FUSE_IN) epsval = 1.0f + *eps_ptr;

    if (STATS) {
        if (t < 128) { Ssum[t] = 0.0f; Ssq[t] = 0.0f; }
    }

    float acc[8][4];
#pragma unroll
    for (int i = 0; i < 8; ++i)
#pragma unroll
        for (int j = 0; j < 4; ++j) acc[i][j] = 0.0f;

    for (int k0 = 0; k0 < 128; k0 += 32) {
#pragma unroll
        for (int jj = 0; jj < 2; ++jj) {
            int j = t + jj * 256;
            int r = j >> 3;
            int c4 = j & 7;
            int row = row0 + r;
            float4 v = make_float4(0.f, 0.f, 0.f, 0.f);
            if (row < n) {
                v = *((const float4*)(A0 + (size_t)row * DD + k0) + c4);
                if (FUSE_IN) {
                    float4 u = *((const float4*)(A1 + (size_t)row * DD + k0) + c4);
                    v.x = epsval * v.x + u.x;
                    v.y = epsval * v.y + u.y;
                    v.z = epsval * v.z + u.z;
                    v.w = epsval * v.w + u.w;
                }
            }
            *(float4*)&As[r][c4 * 4] = v;
        }
#pragma unroll
        for (int jj = 0; jj < 4; ++jj) {
            int j = t + jj * 256;
            int r = j >> 5;
            int c4 = j & 31;
            *(float4*)&Ws[r][c4 * 4] = *((const float4*)(W + (size_t)(k0 + r) * DD) + c4);
        }
        __syncthreads();
#pragma unroll
        for (int kk = 0; kk < 32; ++kk) {
            float4 w = *(float4*)&Ws[kk][cg * 4];
#pragma unroll
            for (int i = 0; i < 8; ++i) {
                float a = As[rg * 8 + i][kk];
                acc[i][0] = fmaf(a, w.x, acc[i][0]);
                acc[i][1] = fmaf(a, w.y, acc[i][1]);
                acc[i][2] = fmaf(a, w.z, acc[i][2]);
                acc[i][3] = fmaf(a, w.w, acc[i][3]);
            }
        }
        __syncthreads();
    }

    const float4 bv = *((const float4*)bias + cg);
    float psum[4] = {0.f, 0.f, 0.f, 0.f};
    float psq[4] = {0.f, 0.f, 0.f, 0.f};
#pragma unroll
    for (int i = 0; i < 8; ++i) {
        int row = row0 + rg * 8 + i;
        float4 o;
        o.x = acc[i][0] + bv.x;
        o.y = acc[i][1] + bv.y;
        o.z = acc[i][2] + bv.z;
        o.w = acc[i][3] + bv.w;
        if (RELU) {
            o.x = fmaxf(o.x, 0.f); o.y = fmaxf(o.y, 0.f);
            o.z = fmaxf(o.z, 0.f); o.w = fmaxf(o.w, 0.f);
        }
        if (row < n) {
            *(float4*)(out + (size_t)row * DD + cg * 4) = o;
            if (STATS) {
                psum[0] += o.x; psum[1] += o.y; psum[2] += o.z; psum[3] += o.w;
                psq[0] += o.x * o.x; psq[1] += o.y * o.y;
                psq[2] += o.z * o.z; psq[3] += o.w * o.w;
            }
        }
    }
    if (STATS) {
        __syncthreads();
        atomicAdd(&Ssum[cg * 4 + 0], psum[0]);
        atomicAdd(&Ssum[cg * 4 + 1], psum[1]);
        atomicAdd(&Ssum[cg * 4 + 2], psum[2]);
        atomicAdd(&Ssum[cg * 4 + 3], psum[3]);
        atomicAdd(&Ssq[cg * 4 + 0], psq[0]);
        atomicAdd(&Ssq[cg * 4 + 1], psq[1]);
        atomicAdd(&Ssq[cg * 4 + 2], psq[2]);
        atomicAdd(&Ssq[cg * 4 + 3], psq[3]);
        __syncthreads();
        if (t < 128) {
            atomicAdd(&stats[t], Ssum[t]);
            atomicAdd(&stats[128 + t], Ssq[t]);
        }
    }
}

// ---------------- BN finalize ----------------
__global__ void bn_finalize(const float* __restrict__ stats,
                            const float* __restrict__ gamma,
                            const float* __restrict__ beta,
                            float* __restrict__ scsh, int n) {
    int c = threadIdx.x;
    float inv_n = 1.0f / (float)n;
    float mean = stats[c] * inv_n;
    float var = stats[128 + c] * inv_n - mean * mean;
    float sc = gamma[c] * rsqrtf(var + BN_EPS);
    scsh[c] = sc;
    scsh[128 + c] = beta[c] - mean * sc;
}

// ---------------- apply: out = h + leaky(z2*scale + shift) ----------------
__global__ void apply_kernel(const float* __restrict__ h,
                             const float* __restrict__ z2,
                             const float* __restrict__ scsh,
                             float* __restrict__ out, int total4) {
    int i = blockIdx.x * blockDim.x + threadIdx.x;
    if (i >= total4) return;
    int c4 = i & 31;
    float4 sc = ((const float4*)scsh)[c4];
    float4 sh = ((const float4*)(scsh + 128))[c4];
    float4 z = ((const float4*)z2)[i];
    float4 hh = ((const float4*)h)[i];
    float4 o;
    float v;
    v = fmaf(z.x, sc.x, sh.x); o.x = hh.x + (v >= 0.f ? v : SLOPE * v);
    v = fmaf(z.y, sc.y, sh.y); o.y = hh.y + (v >= 0.f ? v : SLOPE * v);
    v = fmaf(z.z, sc.z, sh.z); o.z = hh.z + (v >= 0.f ? v : SLOPE * v);
    v = fmaf(z.w, sc.w, sh.w); o.w = hh.w + (v >= 0.f ? v : SLOPE * v);
    ((float4*)out)[i] = o;
}

extern "C" void kernel_launch(void* const* d_in, const int* in_sizes, int n_in,
                              void* d_out, int out_size, void* d_ws, size_t ws_size,
                              hipStream_t stream) {
    const float* h     = (const float*)d_in[0];
    const int*   src   = (const int*)d_in[1];
    const int*   dst   = (const int*)d_in[2];
    const float* eps   = (const float*)d_in[3];
    const float* W1    = (const float*)d_in[4];
    const float* b1    = (const float*)d_in[5];
    const float* W2    = (const float*)d_in[6];
    const float* b2    = (const float*)d_in[7];
    const float* gamma = (const float*)d_in[8];
    const float* beta  = (const float*)d_in[9];
    float* out = (float*)d_out;

    const int n = in_sizes[0] / DD;   // 50000
    const int E = in_sizes[1];        // 1600000
    const int NB = (n + BROWS - 1) / BROWS;   // 782 buckets

    // workspace layout (floats)
    float* ws    = (float*)d_ws;
    float* agg   = ws;                        // n*DD, reused as z2 after GEMM1
    float* z1    = ws + (size_t)n * DD;       // n*DD
    float* stats = ws + (size_t)2 * n * DD;   // 256
    float* scsh  = stats + 256;               // 256
    float* z2    = agg;

    // bucket scratch overlaid on z1 (dead until GEMM1 writes it):
    // bcnt/off/cursor/packed = 3*NB+1+E ints (~6.4 MB) << n*DD floats (25.6 MB)
    int* bcnt        = (int*)z1;
    int* off         = bcnt + NB;          // NB+1 entries
    int* cursor      = off + NB + 1;
    unsigned* packed = (unsigned*)(cursor + NB);

    hipMemsetAsync(bcnt, 0, (size_t)NB * sizeof(int), stream);
    hipMemsetAsync(stats, 0, 256 * sizeof(float), stream);

    {   // coarse bucket build
        histb_kernel<<<256, 256, 0, stream>>>(dst, bcnt, E, NB);
        scanb_kernel<<<1, 1024, 0, stream>>>(bcnt, off, cursor, NB);
        int blocks = (E + 255) / 256;
        scatb_kernel<<<blocks, 256, 0, stream>>>(src, dst, cursor, packed, E);
    }
    {   // bucketed LDS accumulation (atomic-free at HBM level)
        accumb_kernel<<<NB, 256, 0, stream>>>(h, off, packed, agg, n);
    }
    {   // GEMM1: z1 = relu(((1+eps)h + agg) @ W1 + b1)
        int blocks = (n + 63) / 64;
        gemm_kernel<true, true, false><<<blocks, 256, 0, stream>>>(
            h, agg, eps, W1, b1, z1, nullptr, n);
    }
    {   // GEMM2: z2 = z1 @ W2 + b2, with BN stats
        int blocks = (n + 63) / 64;
        gemm_kernel<false, false, true><<<blocks, 256, 0, stream>>>(
            z1, nullptr, nullptr, W2, b2, z2, stats, n);
    }
    bn_finalize<<<1, 128, 0, stream>>>(stats, gamma, beta, scsh, n);
    {   // apply BN + leaky relu + residual
        int total4 = n * DD / 4;
        int blocks = (total4 + 255) / 256;
        apply_kernel<<<blocks, 256, 0, stream>>>(h, z2, scsh, out, total4);
    }
}

// Round 4
// 390.941 us; speedup vs baseline: 4.9484x; 4.9484x over previous
//
#include <hip/hip_runtime.h>
#include <cstddef>

#define DD 128
#define BN_EPS 1e-5f
#define SLOPE 0.01f
#define BSH 6              // 64 dst rows per bucket
#define BROWS 64
#define CPAD 16            // cursor padding (ints) -> one cacheline per cursor
#define CAP 4096           // per-chunk edge capacity in LDS (16 KB)

__device__ __forceinline__ float b2f(unsigned short u) {
    return __uint_as_float(((unsigned)u) << 16);
}
__device__ __forceinline__ unsigned short f2b(float x) {
    unsigned b = __float_as_uint(x);
    b += 0x7fffu + ((b >> 16) & 1u);   // round-to-nearest-even
    return (unsigned short)(b >> 16);
}

// ---------- h (fp32) -> hb (bf16), RNE ----------
__global__ __launch_bounds__(256) void h2b_kernel(const float* __restrict__ h,
                                                  ushort* __restrict__ hb, int total4) {
    int i = blockIdx.x * blockDim.x + threadIdx.x;
    if (i >= total4) return;
    float4 v = ((const float4*)h)[i];
    ushort4 o;
    o.x = f2b(v.x); o.y = f2b(v.y); o.z = f2b(v.z); o.w = f2b(v.w);
    ((ushort4*)hb)[i] = o;
}

// ---------- bucket histogram ----------
__global__ __launch_bounds__(256) void histb_kernel(const int* __restrict__ dst,
                                                    int* __restrict__ bcnt,
                                                    int E, int NB) {
    __shared__ int bins[1024];
    for (int i = threadIdx.x; i < NB; i += blockDim.x) bins[i] = 0;
    __syncthreads();
    for (int e = blockIdx.x * blockDim.x + threadIdx.x; e < E;
         e += gridDim.x * blockDim.x)
        atomicAdd(&bins[dst[e] >> BSH], 1);
    __syncthreads();
    for (int i = threadIdx.x; i < NB; i += blockDim.x)
        if (bins[i]) atomicAdd(&bcnt[i], bins[i]);
}

// ---------- exclusive scan of bucket counts (NB <= 1024) ----------
__global__ __launch_bounds__(1024) void scanb_kernel(const int* __restrict__ bcnt,
                                                     int* __restrict__ off,
                                                     int* __restrict__ cursor, int NB) {
    __shared__ int s[1024];
    const int t = threadIdx.x;
    int v = (t < NB) ? bcnt[t] : 0;
    s[t] = v;
    __syncthreads();
    for (int d = 1; d < 1024; d <<= 1) {
        int u = (t >= d) ? s[t - d] : 0;
        __syncthreads();
        s[t] += u;
        __syncthreads();
    }
    if (t < NB) {
        int excl = s[t] - v;
        off[t] = excl;
        cursor[t * CPAD] = excl;
    }
    if (t == 0) off[NB] = s[1023];
}

// ---------- coarse scatter: packed[pos] = (dst&63)<<16 | src ----------
__global__ __launch_bounds__(256) void scatb_kernel(const int* __restrict__ src,
                                                    const int* __restrict__ dst,
                                                    int* __restrict__ cursor,
                                                    unsigned* __restrict__ packed, int E) {
    int e = blockIdx.x * blockDim.x + threadIdx.x;
    if (e >= E) return;
    int d = dst[e];
    int b = d >> BSH;
    int pos = atomicAdd(&cursor[b * CPAD], 1);
    packed[pos] = ((unsigned)(d & (BROWS - 1)) << 16) | (unsigned)src[e];
}

// ---------- fused per-bucket counting-sort + register gather ----------
// One block per 64-node bucket. Wave w owns 16 nodes; lane l holds elements
// (2l, 2l+1) of each owned node's 128-dim accumulator in registers.
__global__ __launch_bounds__(256) void aggb_kernel(const ushort* __restrict__ hb,
                                                   const int* __restrict__ off,
                                                   const unsigned* __restrict__ packed,
                                                   float* __restrict__ agg, int n) {
    __shared__ int cnt[64];
    __shared__ int cofs[65];
    __shared__ int ccur[64];
    __shared__ unsigned short sbuf[CAP];

    const int t = threadIdx.x;
    const int lane = t & 63;
    const int w = t >> 6;
    const int b = blockIdx.x;
    const int e0 = off[b];
    const int e1 = off[b + 1];

    float2 acc[16];
#pragma unroll
    for (int i = 0; i < 16; ++i) acc[i] = make_float2(0.f, 0.f);

    for (int cs = e0; cs < e1; cs += CAP) {
        const int cn = min(CAP, e1 - cs);
        if (t < 64) cnt[t] = 0;
        __syncthreads();
        for (int i = t; i < cn; i += 256)
            atomicAdd(&cnt[packed[cs + i] >> 16], 1);
        __syncthreads();
        if (t < 64) {
            int v = cnt[t];
            int s = v;
#pragma unroll
            for (int d = 1; d < 64; d <<= 1) {
                int u = __shfl_up(s, d);
                if (lane >= d) s += u;
            }
            cofs[t + 1] = s;
            if (t == 0) cofs[0] = 0;
            ccur[t] = s - v;
        }
        __syncthreads();
        for (int i = t; i < cn; i += 256) {
            unsigned p = packed[cs + i];
            int pos = atomicAdd(&ccur[p >> 16], 1);
            sbuf[pos] = (unsigned short)(p & 0xffffu);
        }
        __syncthreads();

#pragma unroll 1
        for (int i = 0; i < 16; ++i) {
            const int ld = w * 16 + i;
            const int jb = cofs[ld];
            const int je = cofs[ld + 1];
            float2 a = acc[i];
            int j = jb;
            for (; j + 4 <= je; j += 4) {
                int s0 = sbuf[j + 0];
                int s1 = sbuf[j + 1];
                int s2 = sbuf[j + 2];
                int s3 = sbuf[j + 3];
                ushort2 u0 = ((const ushort2*)(hb + (size_t)s0 * DD))[lane];
                ushort2 u1 = ((const ushort2*)(hb + (size_t)s1 * DD))[lane];
                ushort2 u2 = ((const ushort2*)(hb + (size_t)s2 * DD))[lane];
                ushort2 u3 = ((const ushort2*)(hb + (size_t)s3 * DD))[lane];
                a.x += (b2f(u0.x) + b2f(u1.x)) + (b2f(u2.x) + b2f(u3.x));
                a.y += (b2f(u0.y) + b2f(u1.y)) + (b2f(u2.y) + b2f(u3.y));
            }
            for (; j < je; ++j) {
                int s0 = sbuf[j];
                ushort2 u0 = ((const ushort2*)(hb + (size_t)s0 * DD))[lane];
                a.x += b2f(u0.x);
                a.y += b2f(u0.y);
            }
            acc[i] = a;
        }
        __syncthreads();
    }

    const int r0 = b << BSH;
#pragma unroll 1
    for (int i = 0; i < 16; ++i) {
        int u = r0 + w * 16 + i;
        if (u < n)
            ((float2*)(agg + (size_t)u * DD))[lane] = acc[i];
    }
}

// ---------------- GEMM: out[n,128] = act(A[n,128] @ W[128,128] + bias) ----
template <bool FUSE_IN, bool RELU, bool STATS>
__global__ __launch_bounds__(256) void gemm_kernel(
        const float* __restrict__ A0, const float* __restrict__ A1,
        const float* __restrict__ eps_ptr,
        const float* __restrict__ W, const float* __restrict__ bias,
        float* __restrict__ out, float* __restrict__ stats, int n) {
    __shared__ float As[64][36];
    __shared__ float Ws[32][128];
    __shared__ float Ssum[128];
    __shared__ float Ssq[128];

    const int t = threadIdx.x;
    const int cg = t & 31;
    const int rg = t >> 5;
    const int row0 = blockIdx.x * 64;

    float epsval = 1.0f;
    if (FUSE_IN) epsval = 1.0f + *eps_ptr;

    if (STATS) {
        if (t < 128) { Ssum[t] = 0.0f; Ssq[t] = 0.0f; }
    }

    float acc[8][4];
#pragma unroll
    for (int i = 0; i < 8; ++i)
#pragma unroll
        for (int j = 0; j < 4; ++j) acc[i][j] = 0.0f;

    for (int k0 = 0; k0 < 128; k0 += 32) {
#pragma unroll
        for (int jj = 0; jj < 2; ++jj) {
            int j = t + jj * 256;
            int r = j >> 3;
            int c4 = j & 7;
            int row = row0 + r;
            float4 v = make_float4(0.f, 0.f, 0.f, 0.f);
            if (row < n) {
                v = *((const float4*)(A0 + (size_t)row * DD + k0) + c4);
                if (FUSE_IN) {
                    float4 u = *((const float4*)(A1 + (size_t)row * DD + k0) + c4);
                    v.x = epsval * v.x + u.x;
                    v.y = epsval * v.y + u.y;
                    v.z = epsval * v.z + u.z;
                    v.w = epsval * v.w + u.w;
                }
            }
            *(float4*)&As[r][c4 * 4] = v;
        }
#pragma unroll
        for (int jj = 0; jj < 4; ++jj) {
            int j = t + jj * 256;
            int r = j >> 5;
            int c4 = j & 31;
            *(float4*)&Ws[r][c4 * 4] = *((const float4*)(W + (size_t)(k0 + r) * DD) + c4);
        }
        __syncthreads();
#pragma unroll
        for (int kk = 0; kk < 32; ++kk) {
            float4 w = *(float4*)&Ws[kk][cg * 4];
#pragma unroll
            for (int i = 0; i < 8; ++i) {
                float a = As[rg * 8 + i][kk];
                acc[i][0] = fmaf(a, w.x, acc[i][0]);
                acc[i][1] = fmaf(a, w.y, acc[i][1]);
                acc[i][2] = fmaf(a, w.z, acc[i][2]);
                acc[i][3] = fmaf(a, w.w, acc[i][3]);
            }
        }
        __syncthreads();
    }

    const float4 bv = *((const float4*)bias + cg);
    float psum[4] = {0.f, 0.f, 0.f, 0.f};
    float psq[4] = {0.f, 0.f, 0.f, 0.f};
#pragma unroll
    for (int i = 0; i < 8; ++i) {
        int row = row0 + rg * 8 + i;
        float4 o;
        o.x = acc[i][0] + bv.x;
        o.y = acc[i][1] + bv.y;
        o.z = acc[i][2] + bv.z;
        o.w = acc[i][3] + bv.w;
        if (RELU) {
            o.x = fmaxf(o.x, 0.f); o.y = fmaxf(o.y, 0.f);
            o.z = fmaxf(o.z, 0.f); o.w = fmaxf(o.w, 0.f);
        }
        if (row < n) {
            *(float4*)(out + (size_t)row * DD + cg * 4) = o;
            if (STATS) {
                psum[0] += o.x; psum[1] += o.y; psum[2] += o.z; psum[3] += o.w;
                psq[0] += o.x * o.x; psq[1] += o.y * o.y;
                psq[2] += o.z * o.z; psq[3] += o.w * o.w;
            }
        }
    }
    if (STATS) {
        __syncthreads();
        atomicAdd(&Ssum[cg * 4 + 0], psum[0]);
        atomicAdd(&Ssum[cg * 4 + 1], psum[1]);
        atomicAdd(&Ssum[cg * 4 + 2], psum[2]);
        atomicAdd(&Ssum[cg * 4 + 3], psum[3]);
        atomicAdd(&Ssq[cg * 4 + 0], psq[0]);
        atomicAdd(&Ssq[cg * 4 + 1], psq[1]);
        atomicAdd(&Ssq[cg * 4 + 2], psq[2]);
        atomicAdd(&Ssq[cg * 4 + 3], psq[3]);
        __syncthreads();
        if (t < 128) {
            atomicAdd(&stats[t], Ssum[t]);
            atomicAdd(&stats[128 + t], Ssq[t]);
        }
    }
}

// ---------------- BN finalize ----------------
__global__ void bn_finalize(const float* __restrict__ stats,
                            const float* __restrict__ gamma,
                            const float* __restrict__ beta,
                            float* __restrict__ scsh, int n) {
    int c = threadIdx.x;
    float inv_n = 1.0f / (float)n;
    float mean = stats[c] * inv_n;
    float var = stats[128 + c] * inv_n - mean * mean;
    float sc = gamma[c] * rsqrtf(var + BN_EPS);
    scsh[c] = sc;
    scsh[128 + c] = beta[c] - mean * sc;
}

// ---------------- apply: out = h + leaky(z2*scale + shift) ----------------
__global__ void apply_kernel(const float* __restrict__ h,
                             const float* __restrict__ z2,
                             const float* __restrict__ scsh,
                             float* __restrict__ out, int total4) {
    int i = blockIdx.x * blockDim.x + threadIdx.x;
    if (i >= total4) return;
    int c4 = i & 31;
    float4 sc = ((const float4*)scsh)[c4];
    float4 sh = ((const float4*)(scsh + 128))[c4];
    float4 z = ((const float4*)z2)[i];
    float4 hh = ((const float4*)h)[i];
    float4 o;
    float v;
    v = fmaf(z.x, sc.x, sh.x); o.x = hh.x + (v >= 0.f ? v : SLOPE * v);
    v = fmaf(z.y, sc.y, sh.y); o.y = hh.y + (v >= 0.f ? v : SLOPE * v);
    v = fmaf(z.z, sc.z, sh.z); o.z = hh.z + (v >= 0.f ? v : SLOPE * v);
    v = fmaf(z.w, sc.w, sh.w); o.w = hh.w + (v >= 0.f ? v : SLOPE * v);
    ((float4*)out)[i] = o;
}

extern "C" void kernel_launch(void* const* d_in, const int* in_sizes, int n_in,
                              void* d_out, int out_size, void* d_ws, size_t ws_size,
                              hipStream_t stream) {
    const float* h     = (const float*)d_in[0];
    const int*   src   = (const int*)d_in[1];
    const int*   dst   = (const int*)d_in[2];
    const float* eps   = (const float*)d_in[3];
    const float* W1    = (const float*)d_in[4];
    const float* b1    = (const float*)d_in[5];
    const float* W2    = (const float*)d_in[6];
    const float* b2    = (const float*)d_in[7];
    const float* gamma = (const float*)d_in[8];
    const float* beta  = (const float*)d_in[9];
    float* out = (float*)d_out;

    const int n = in_sizes[0] / DD;   // 50000
    const int E = in_sizes[1];        // 1600000
    const int NB = (n + BROWS - 1) / BROWS;   // 782 buckets

    // workspace layout (floats)
    float* ws    = (float*)d_ws;
    float* agg   = ws;                        // n*DD, reused as z2 after GEMM1
    float* z1    = ws + (size_t)n * DD;       // n*DD
    float* stats = ws + (size_t)2 * n * DD;   // 256
    float* scsh  = stats + 256;               // 256
    float* z2    = agg;

    // scratch overlaid on z1 (dead until GEMM1 writes it):
    // bcnt NB + off NB+1 + cursor NB*CPAD + packed E + hb n*DD/2 ints ~= 19.3 MB < 25.6 MB
    int* bcnt        = (int*)z1;
    int* off         = bcnt + NB;
    int* cursor      = off + NB + 1;
    unsigned* packed = (unsigned*)(cursor + (size_t)NB * CPAD);
    ushort* hb       = (ushort*)(packed + E);

    hipMemsetAsync(bcnt, 0, (size_t)NB * sizeof(int), stream);
    hipMemsetAsync(stats, 0, 256 * sizeof(float), stream);

    {   // h -> bf16
        int total4 = n * DD / 4;
        h2b_kernel<<<(total4 + 255) / 256, 256, 0, stream>>>(h, hb, total4);
    }
    {   // coarse bucket build
        histb_kernel<<<256, 256, 0, stream>>>(dst, bcnt, E, NB);
        scanb_kernel<<<1, 1024, 0, stream>>>(bcnt, off, cursor, NB);
        scatb_kernel<<<(E + 255) / 256, 256, 0, stream>>>(src, dst, cursor, packed, E);
    }
    {   // fused sort + gather (register accumulation, no atomics on hot path)
        aggb_kernel<<<NB, 256, 0, stream>>>(hb, off, packed, agg, n);
    }
    {   // GEMM1: z1 = relu(((1+eps)h + agg) @ W1 + b1)
        int blocks = (n + 63) / 64;
        gemm_kernel<true, true, false><<<blocks, 256, 0, stream>>>(
            h, agg, eps, W1, b1, z1, nullptr, n);
    }
    {   // GEMM2: z2 = z1 @ W2 + b2, with BN stats
        int blocks = (n + 63) / 64;
        gemm_kernel<false, false, true><<<blocks, 256, 0, stream>>>(
            z1, nullptr, nullptr, W2, b2, z2, stats, n);
    }
    bn_finalize<<<1, 128, 0, stream>>>(stats, gamma, beta, scsh, n);
    {   // apply BN + leaky relu + residual
        int total4 = n * DD / 4;
        int blocks = (total4 + 255) / 256;
        apply_kernel<<<blocks, 256, 0, stream>>>(h, z2, scsh, out, total4);
    }
}

// Round 5
// 337.809 us; speedup vs baseline: 5.7267x; 1.1573x over previous
//
#include <hip/hip_runtime.h>
#include <cstddef>

#define DD 128
#define BN_EPS 1e-5f
#define SLOPE 0.01f
#define BSH 6              // 64 dst rows per bucket
#define BROWS 64
#define CPAD 16            // cursor padding (ints) -> one cacheline per cursor
#define CAP 4096           // aggb per-chunk edge capacity in LDS
#define SCHUNK 4096        // scatb per-block edge chunk
#define CSH 13             // src-chunk shift: 8192 rows = 2 MB bf16, L2-resident
#define NCH 7              // ceil(50000/8192)

__device__ __forceinline__ float b2f(unsigned short u) {
    return __uint_as_float(((unsigned)u) << 16);
}
__device__ __forceinline__ unsigned short f2b(float x) {
    unsigned b = __float_as_uint(x);
    b += 0x7fffu + ((b >> 16) & 1u);   // round-to-nearest-even
    return (unsigned short)(b >> 16);
}

// ---------- h (fp32) -> hb (bf16), RNE ----------
__global__ __launch_bounds__(256) void h2b_kernel(const float* __restrict__ h,
                                                  ushort* __restrict__ hb, int total4) {
    int i = blockIdx.x * blockDim.x + threadIdx.x;
    if (i >= total4) return;
    float4 v = ((const float4*)h)[i];
    ushort4 o;
    o.x = f2b(v.x); o.y = f2b(v.y); o.z = f2b(v.z); o.w = f2b(v.w);
    ((ushort4*)hb)[i] = o;
}

// ---------- bucket histogram ----------
__global__ __launch_bounds__(256) void histb_kernel(const int* __restrict__ dst,
                                                    int* __restrict__ bcnt,
                                                    int E, int NB) {
    __shared__ int bins[1024];
    for (int i = threadIdx.x; i < NB; i += blockDim.x) bins[i] = 0;
    __syncthreads();
    for (int e = blockIdx.x * blockDim.x + threadIdx.x; e < E;
         e += gridDim.x * blockDim.x)
        atomicAdd(&bins[dst[e] >> BSH], 1);
    __syncthreads();
    for (int i = threadIdx.x; i < NB; i += blockDim.x)
        if (bins[i]) atomicAdd(&bcnt[i], bins[i]);
}

// ---------- exclusive scan of bucket counts (NB <= 1024) ----------
__global__ __launch_bounds__(1024) void scanb_kernel(const int* __restrict__ bcnt,
                                                     int* __restrict__ off,
                                                     int* __restrict__ cursor, int NB) {
    __shared__ int s[1024];
    const int t = threadIdx.x;
    int v = (t < NB) ? bcnt[t] : 0;
    s[t] = v;
    __syncthreads();
    for (int d = 1; d < 1024; d <<= 1) {
        int u = (t >= d) ? s[t - d] : 0;
        __syncthreads();
        s[t] += u;
        __syncthreads();
    }
    if (t < NB) {
        int excl = s[t] - v;
        off[t] = excl;
        cursor[t * CPAD] = excl;
    }
    if (t == 0) off[NB] = s[1023];
}

// ---------- sorted chunk scatter ----------
// Each block counting-sorts SCHUNK edges by bucket in LDS, reserves one
// contiguous global run per (block,bucket) with a single atomicAdd, then
// copies runs out coalesced. packed = bucket<<22 | ldst<<16 | src (src<65536).
__global__ __launch_bounds__(256) void scatb2_kernel(const int* __restrict__ src,
                                                     const int* __restrict__ dst,
                                                     int* __restrict__ cursor,
                                                     unsigned* __restrict__ packed,
                                                     int E, int NB) {
    __shared__ int bins[1024];
    __shared__ int lofs[1024];
    __shared__ int lcur[1024];
    __shared__ int gbase[1024];
    __shared__ unsigned sbuf[SCHUNK];
    __shared__ int wtot[4];

    const int t = threadIdx.x;
    const int lane = t & 63;
    const int w = t >> 6;
    const int cs = blockIdx.x * SCHUNK;
    const int cn = min(SCHUNK, E - cs);

#pragma unroll
    for (int k = 0; k < 4; ++k) bins[t + 256 * k] = 0;
    __syncthreads();
    for (int i = t; i < cn; i += 256) atomicAdd(&bins[dst[cs + i] >> BSH], 1);
    __syncthreads();

    // block-wide exclusive scan of 1024 bins (4 per thread)
    const int b0 = 4 * t;
    int c0 = bins[b0], c1 = bins[b0 + 1], c2 = bins[b0 + 2], c3 = bins[b0 + 3];
    int s = c0 + c1 + c2 + c3;
    int si = s;
#pragma unroll
    for (int d = 1; d < 64; d <<= 1) {
        int u = __shfl_up(si, d);
        if (lane >= d) si += u;
    }
    if (lane == 63) wtot[w] = si;
    __syncthreads();
    if (t == 0) {
        int a = 0;
#pragma unroll
        for (int k = 0; k < 4; ++k) { int v = wtot[k]; wtot[k] = a; a += v; }
    }
    __syncthreads();
    int excl = wtot[w] + si - s;
    lofs[b0] = excl; lcur[b0] = excl;
    lofs[b0 + 1] = excl + c0; lcur[b0 + 1] = excl + c0;
    lofs[b0 + 2] = excl + c0 + c1; lcur[b0 + 2] = excl + c0 + c1;
    lofs[b0 + 3] = excl + c0 + c1 + c2; lcur[b0 + 3] = excl + c0 + c1 + c2;
    __syncthreads();

    // reserve one global run per non-empty bucket
    for (int b = t; b < NB; b += 256) {
        int c = bins[b];
        if (c) gbase[b] = atomicAdd(&cursor[b * CPAD], c) - lofs[b];
    }
    // place into LDS sorted by bucket
    for (int i = t; i < cn; i += 256) {
        int d = dst[cs + i];
        int b = d >> BSH;
        int pos = atomicAdd(&lcur[b], 1);
        sbuf[pos] = ((unsigned)b << 22) | ((unsigned)(d & (BROWS - 1)) << 16)
                    | (unsigned)src[cs + i];
    }
    __syncthreads();
    // copy runs out (consecutive i within a run -> consecutive global addrs)
    for (int i = t; i < cn; i += 256) {
        unsigned p = sbuf[i];
        int b = (int)(p >> 22);
        packed[gbase[b] + i] = p;
    }
}

// ---------- fused per-bucket counting-sort + register gather ----------
// Sort key = (src>>CSH)*64 + ldst: chunk-major ordering keeps the chip-wide
// hot h-window ~2 MB (per-XCD L2 resident). acc[] statically indexed ->
// registers (R4's dynamic indexing spilled to scratch: 50 MB extra WRITE).
__global__ __launch_bounds__(256) void aggb2_kernel(const ushort* __restrict__ hb,
                                                    const int* __restrict__ off,
                                                    const unsigned* __restrict__ packed,
                                                    float* __restrict__ agg, int n) {
    __shared__ int bins[512];
    __shared__ int cofs[513];
    __shared__ int ccur[512];
    __shared__ unsigned short sbuf[CAP];
    __shared__ int wtot[4];

    const int t = threadIdx.x;
    const int lane = t & 63;
    const int w = t >> 6;
    const int b = blockIdx.x;
    const int e0 = off[b];
    const int e1 = off[b + 1];

    float2 acc[16];
#pragma unroll
    for (int i = 0; i < 16; ++i) acc[i] = make_float2(0.f, 0.f);

    for (int cs = e0; cs < e1; cs += CAP) {
        const int cn = min(CAP, e1 - cs);
        bins[t] = 0; bins[t + 256] = 0;
        __syncthreads();
        for (int i = t; i < cn; i += 256) {
            unsigned p = packed[cs + i];
            int key = (int)((((p & 0xffffu) >> CSH) << 6) | ((p >> 16) & 63u));
            atomicAdd(&bins[key], 1);
        }
        __syncthreads();
        // scan 512 bins (2 per thread)
        int c0 = bins[2 * t], c1 = bins[2 * t + 1];
        int s = c0 + c1;
        int si = s;
#pragma unroll
        for (int d = 1; d < 64; d <<= 1) {
            int u = __shfl_up(si, d);
            if (lane >= d) si += u;
        }
        if (lane == 63) wtot[w] = si;
        __syncthreads();
        if (t == 0) {
            int a = 0;
#pragma unroll
            for (int k = 0; k < 4; ++k) { int v = wtot[k]; wtot[k] = a; a += v; }
        }
        __syncthreads();
        int excl = wtot[w] + si - s;
        cofs[2 * t] = excl;     ccur[2 * t] = excl;
        cofs[2 * t + 1] = excl + c0; ccur[2 * t + 1] = excl + c0;
        if (t == 255) cofs[512] = excl + c0 + c1;
        __syncthreads();
        for (int i = t; i < cn; i += 256) {
            unsigned p = packed[cs + i];
            int key = (int)((((p & 0xffffu) >> CSH) << 6) | ((p >> 16) & 63u));
            int pos = atomicAdd(&ccur[key], 1);
            sbuf[pos] = (unsigned short)(p & 0xffffu);
        }
        __syncthreads();

        for (int c = 0; c < NCH; ++c) {
            const int kbase = c * 64 + w * 16;
#pragma unroll
            for (int i = 0; i < 16; ++i) {
                const int jb = cofs[kbase + i];
                const int je = cofs[kbase + i + 1];
                float2 a = acc[i];
                int j = jb;
                for (; j + 4 <= je; j += 4) {
                    int s0 = sbuf[j + 0];
                    int s1 = sbuf[j + 1];
                    int s2 = sbuf[j + 2];
                    int s3 = sbuf[j + 3];
                    ushort2 u0 = ((const ushort2*)(hb + (size_t)s0 * DD))[lane];
                    ushort2 u1 = ((const ushort2*)(hb + (size_t)s1 * DD))[lane];
                    ushort2 u2 = ((const ushort2*)(hb + (size_t)s2 * DD))[lane];
                    ushort2 u3 = ((const ushort2*)(hb + (size_t)s3 * DD))[lane];
                    a.x += (b2f(u0.x) + b2f(u1.x)) + (b2f(u2.x) + b2f(u3.x));
                    a.y += (b2f(u0.y) + b2f(u1.y)) + (b2f(u2.y) + b2f(u3.y));
                }
                for (; j < je; ++j) {
                    int s0 = sbuf[j];
                    ushort2 u0 = ((const ushort2*)(hb + (size_t)s0 * DD))[lane];
                    a.x += b2f(u0.x);
                    a.y += b2f(u0.y);
                }
                acc[i] = a;
            }
        }
        __syncthreads();
    }

    const int r0 = b << BSH;
#pragma unroll
    for (int i = 0; i < 16; ++i) {
        int u = r0 + w * 16 + i;
        if (u < n)
            ((float2*)(agg + (size_t)u * DD))[lane] = acc[i];
    }
}

// ---------------- GEMM: out[n,128] = act(A[n,128] @ W[128,128] + bias) ----
template <bool FUSE_IN, bool RELU, bool STATS>
__global__ __launch_bounds__(256) void gemm_kernel(
        const float* __restrict__ A0, const float* __restrict__ A1,
        const float* __restrict__ eps_ptr,
        const float* __restrict__ W, const float* __restrict__ bias,
        float* __restrict__ out, float* __restrict__ stats, int n) {
    __shared__ float As[64][36];
    __shared__ float Ws[32][128];
    __shared__ float Ssum[128];
    __shared__ float Ssq[128];

    const int t = threadIdx.x;
    const int cg = t & 31;
    const int rg = t >> 5;
    const int row0 = blockIdx.x * 64;

    float epsval = 1.0f;
    if (FUSE_IN) epsval = 1.0f + *eps_ptr;

    if (STATS) {
        if (t < 128) { Ssum[t] = 0.0f; Ssq[t] = 0.0f; }
    }

    float acc[8][4];
#pragma unroll
    for (int i = 0; i < 8; ++i)
#pragma unroll
        for (int j = 0; j < 4; ++j) acc[i][j] = 0.0f;

    for (int k0 = 0; k0 < 128; k0 += 32) {
#pragma unroll
        for (int jj = 0; jj < 2; ++jj) {
            int j = t + jj * 256;
            int r = j >> 3;
            int c4 = j & 7;
            int row = row0 + r;
            float4 v = make_float4(0.f, 0.f, 0.f, 0.f);
            if (row < n) {
                v = *((const float4*)(A0 + (size_t)row * DD + k0) + c4);
                if (FUSE_IN) {
                    float4 u = *((const float4*)(A1 + (size_t)row * DD + k0) + c4);
                    v.x = epsval * v.x + u.x;
                    v.y = epsval * v.y + u.y;
                    v.z = epsval * v.z + u.z;
                    v.w = epsval * v.w + u.w;
                }
            }
            *(float4*)&As[r][c4 * 4] = v;
        }
#pragma unroll
        for (int jj = 0; jj < 4; ++jj) {
            int j = t + jj * 256;
            int r = j >> 5;
            int c4 = j & 31;
            *(float4*)&Ws[r][c4 * 4] = *((const float4*)(W + (size_t)(k0 + r) * DD) + c4);
        }
        __syncthreads();
#pragma unroll
        for (int kk = 0; kk < 32; ++kk) {
            float4 w = *(float4*)&Ws[kk][cg * 4];
#pragma unroll
            for (int i = 0; i < 8; ++i) {
                float a = As[rg * 8 + i][kk];
                acc[i][0] = fmaf(a, w.x, acc[i][0]);
                acc[i][1] = fmaf(a, w.y, acc[i][1]);
                acc[i][2] = fmaf(a, w.z, acc[i][2]);
                acc[i][3] = fmaf(a, w.w, acc[i][3]);
            }
        }
        __syncthreads();
    }

    const float4 bv = *((const float4*)bias + cg);
    float psum[4] = {0.f, 0.f, 0.f, 0.f};
    float psq[4] = {0.f, 0.f, 0.f, 0.f};
#pragma unroll
    for (int i = 0; i < 8; ++i) {
        int row = row0 + rg * 8 + i;
        float4 o;
        o.x = acc[i][0] + bv.x;
        o.y = acc[i][1] + bv.y;
        o.z = acc[i][2] + bv.z;
        o.w = acc[i][3] + bv.w;
        if (RELU) {
            o.x = fmaxf(o.x, 0.f); o.y = fmaxf(o.y, 0.f);
            o.z = fmaxf(o.z, 0.f); o.w = fmaxf(o.w, 0.f);
        }
        if (row < n) {
            *(float4*)(out + (size_t)row * DD + cg * 4) = o;
            if (STATS) {
                psum[0] += o.x; psum[1] += o.y; psum[2] += o.z; psum[3] += o.w;
                psq[0] += o.x * o.x; psq[1] += o.y * o.y;
                psq[2] += o.z * o.z; psq[3] += o.w * o.w;
            }
        }
    }
    if (STATS) {
        __syncthreads();
        atomicAdd(&Ssum[cg * 4 + 0], psum[0]);
        atomicAdd(&Ssum[cg * 4 + 1], psum[1]);
        atomicAdd(&Ssum[cg * 4 + 2], psum[2]);
        atomicAdd(&Ssum[cg * 4 + 3], psum[3]);
        atomicAdd(&Ssq[cg * 4 + 0], psq[0]);
        atomicAdd(&Ssq[cg * 4 + 1], psq[1]);
        atomicAdd(&Ssq[cg * 4 + 2], psq[2]);
        atomicAdd(&Ssq[cg * 4 + 3], psq[3]);
        __syncthreads();
        if (t < 128) {
            atomicAdd(&stats[t], Ssum[t]);
            atomicAdd(&stats[128 + t], Ssq[t]);
        }
    }
}

// ---------------- BN finalize ----------------
__global__ void bn_finalize(const float* __restrict__ stats,
                            const float* __restrict__ gamma,
                            const float* __restrict__ beta,
                            float* __restrict__ scsh, int n) {
    int c = threadIdx.x;
    float inv_n = 1.0f / (float)n;
    float mean = stats[c] * inv_n;
    float var = stats[128 + c] * inv_n - mean * mean;
    float sc = gamma[c] * rsqrtf(var + BN_EPS);
    scsh[c] = sc;
    scsh[128 + c] = beta[c] - mean * sc;
}

// ---------------- apply: out = h + leaky(z2*scale + shift) ----------------
__global__ void apply_kernel(const float* __restrict__ h,
                             const float* __restrict__ z2,
                             const float* __restrict__ scsh,
                             float* __restrict__ out, int total4) {
    int i = blockIdx.x * blockDim.x + threadIdx.x;
    if (i >= total4) return;
    int c4 = i & 31;
    float4 sc = ((const float4*)scsh)[c4];
    float4 sh = ((const float4*)(scsh + 128))[c4];
    float4 z = ((const float4*)z2)[i];
    float4 hh = ((const float4*)h)[i];
    float4 o;
    float v;
    v = fmaf(z.x, sc.x, sh.x); o.x = hh.x + (v >= 0.f ? v : SLOPE * v);
    v = fmaf(z.y, sc.y, sh.y); o.y = hh.y + (v >= 0.f ? v : SLOPE * v);
    v = fmaf(z.z, sc.z, sh.z); o.z = hh.z + (v >= 0.f ? v : SLOPE * v);
    v = fmaf(z.w, sc.w, sh.w); o.w = hh.w + (v >= 0.f ? v : SLOPE * v);
    ((float4*)out)[i] = o;
}

extern "C" void kernel_launch(void* const* d_in, const int* in_sizes, int n_in,
                              void* d_out, int out_size, void* d_ws, size_t ws_size,
                              hipStream_t stream) {
    const float* h     = (const float*)d_in[0];
    const int*   src   = (const int*)d_in[1];
    const int*   dst   = (const int*)d_in[2];
    const float* eps   = (const float*)d_in[3];
    const float* W1    = (const float*)d_in[4];
    const float* b1    = (const float*)d_in[5];
    const float* W2    = (const float*)d_in[6];
    const float* b2    = (const float*)d_in[7];
    const float* gamma = (const float*)d_in[8];
    const float* beta  = (const float*)d_in[9];
    float* out = (float*)d_out;

    const int n = in_sizes[0] / DD;   // 50000
    const int E = in_sizes[1];        // 1600000
    const int NB = (n + BROWS - 1) / BROWS;   // 782 buckets

    // workspace layout (floats)
    float* ws    = (float*)d_ws;
    float* agg   = ws;                        // n*DD, reused as z2 after GEMM1
    float* z1    = ws + (size_t)n * DD;       // n*DD
    float* stats = ws + (size_t)2 * n * DD;   // 256
    float* scsh  = stats + 256;               // 256
    float* z2    = agg;

    // scratch overlaid on z1 (dead until GEMM1 writes it):
    int* bcnt        = (int*)z1;
    int* off         = bcnt + NB;
    int* cursor      = off + NB + 1;
    unsigned* packed = (unsigned*)(cursor + (size_t)NB * CPAD);
    ushort* hb       = (ushort*)(packed + E);

    hipMemsetAsync(bcnt, 0, (size_t)NB * sizeof(int), stream);
    hipMemsetAsync(stats, 0, 256 * sizeof(float), stream);

    {   // h -> bf16
        int total4 = n * DD / 4;
        h2b_kernel<<<(total4 + 255) / 256, 256, 0, stream>>>(h, hb, total4);
    }
    {   // coarse bucket build
        histb_kernel<<<256, 256, 0, stream>>>(dst, bcnt, E, NB);
        scanb_kernel<<<1, 1024, 0, stream>>>(bcnt, off, cursor, NB);
        scatb2_kernel<<<(E + SCHUNK - 1) / SCHUNK, 256, 0, stream>>>(
            src, dst, cursor, packed, E, NB);
    }
    {   // fused sort + gather (register accumulation, chunk-major L2 locality)
        aggb2_kernel<<<NB, 256, 0, stream>>>(hb, off, packed, agg, n);
    }
    {   // GEMM1: z1 = relu(((1+eps)h + agg) @ W1 + b1)
        int blocks = (n + 63) / 64;
        gemm_kernel<true, true, false><<<blocks, 256, 0, stream>>>(
            h, agg, eps, W1, b1, z1, nullptr, n);
    }
    {   // GEMM2: z2 = z1 @ W2 + b2, with BN stats
        int blocks = (n + 63) / 64;
        gemm_kernel<false, false, true><<<blocks, 256, 0, stream>>>(
            z1, nullptr, nullptr, W2, b2, z2, stats, n);
    }
    bn_finalize<<<1, 128, 0, stream>>>(stats, gamma, beta, scsh, n);
    {   // apply BN + leaky relu + residual
        int total4 = n * DD / 4;
        int blocks = (total4 + 255) / 256;
        apply_kernel<<<blocks, 256, 0, stream>>>(h, z2, scsh, out, total4);
    }
}